// Round 8
// baseline (50.900 us; speedup 1.0000x reference)
//
#include <hip/hip_runtime.h>
#include <hip/hip_bf16.h>

typedef __attribute__((ext_vector_type(8))) short short8_t;
typedef __attribute__((ext_vector_type(4))) float f32x4;

#define BATCH 64
#define L0 16384
#define L1 8192
#define NPG 4096
#define CF 8
#define H 64
#define CHUNK 128
#define NCHUNK 32
#define NCHUNKS_TOTAL 2048
#define GRID 1024
#define CPB 2

// ---- LDS arena (bytes). Chunk regions alias prologue scratch (time-disjoint).
#define A_X    0        // [536] f32 = 2144   (inside h1 region; dead by phase D)
#define A_H1   0        // [130][72] ushort = 18720
#define A_T1   18720    // [266][8] ushort  = 4256 -> 22976
#define A_ND   22976    // [132][8] ushort  = 2112 -> 25088
#define A_RED  25088    // [4][64] f32      = 1024 -> 26112
#define A_W2T  26112    // [8][64][8] ushort= 8192 -> 34304  (persistent)
// prologue scratch (dead after prologue):
#define P_RG2  0        // [2048] f32 = 8192 (g2w half)
#define P_RG1  8192     // [512] f32  = 2048
#define P_RC2  10240    // [192] f32  = 768
#define P_W1T  19200    // [4][64][8] ushort = 4096
#define P_WCT  23296    // [64][8] ushort    = 1024
#define ARENA_BYTES 34304

__device__ __forceinline__ float disv(int p) {
    if (p < 0 || p >= NPG) return 0.f;
    if (p == 0 || p == NPG - 1) return 0.70710678118654752f;  // 1/sqrt(2)
    return 0.57735026918962576f;                              // 1/sqrt(3)
}
__device__ __forceinline__ unsigned pack_bf2(float a, float b) {
    union { __hip_bfloat162 h2; unsigned u; } cv;
    cv.h2 = __float22bfloat162_rn(make_float2(a, b));
    return cv.u;
}
__device__ __forceinline__ unsigned short bfu(float f) {
    union { __hip_bfloat16 h; unsigned short u; } cv;
    cv.h = __float2bfloat16(f);
    return cv.u;
}
__device__ __forceinline__ float lof(unsigned u) { return __uint_as_float(u << 16); }
__device__ __forceinline__ float hif(unsigned u) { return __uint_as_float(u & 0xffff0000u); }

__global__ __launch_bounds__(256, 4) void k_fused(const float* __restrict__ x,
        const float* __restrict__ c1w, const float* __restrict__ c1b,
        const float* __restrict__ c2w, const float* __restrict__ c2b,
        const float* __restrict__ g1w, const float* __restrict__ g1b,
        const float* __restrict__ g2w, const float* __restrict__ g2b,
        const float* __restrict__ fcw, const float* __restrict__ fcb,
        float* __restrict__ out) {
    __shared__ __align__(16) char arena[ARENA_BYTES];
    float*          x_l  = (float*)(arena + A_X);
    unsigned short* t1_l = (unsigned short*)(arena + A_T1);
    unsigned short* nd_l = (unsigned short*)(arena + A_ND);
    unsigned short* h1_l = (unsigned short*)(arena + A_H1);
    unsigned short* w2t  = (unsigned short*)(arena + A_W2T);
    float*          red  = (float*)(arena + A_RED);
    float*          rg2  = (float*)(arena + P_RG2);
    float*          rg1  = (float*)(arena + P_RG1);
    float*          rc2  = (float*)(arena + P_RC2);
    unsigned short* w1t  = (unsigned short*)(arena + P_W1T);
    unsigned short* wct  = (unsigned short*)(arena + P_WCT);

    const int tid = threadIdx.x;
    const int wave = tid >> 6;
    const int l = tid & 63;
    const int m = l & 15, q = l >> 4;
    const float T = 1.f / 3.f;
    const f32x4 z4 = {0.f, 0.f, 0.f, 0.f};

    // ================= prologue: coalesced weight staging + frag build =====
    for (int e = tid; e < 2048; e += 256) rg2[e] = g2w[e];          // rows 0..31
    for (int e = tid; e < 512; e += 256) rg1[e] = g1w[e];
    if (tid < 192) rc2[tid] = c2w[tid];
    __syncthreads();
    for (int e = tid; e < 2048; e += 256) {        // w2t ks=0 (x 1/3)
        int i = e & 7, lane = (e >> 3) & 63, ct = e >> 9;
        int k = (lane >> 4) * 8 + i;
        int n = ct * 16 + (lane & 15);
        w2t[(ct * 2 + 0) * 512 + (e & 511)] = bfu(rg2[k * H + n] * T);
    }
    __syncthreads();
    for (int e = tid; e < 2048; e += 256) rg2[e] = g2w[2048 + e];   // rows 32..63
    __syncthreads();
    for (int e = tid; e < 2048; e += 256) {        // w2t ks=1 (x 1/3)
        int i = e & 7, lane = (e >> 3) & 63, ct = e >> 9;
        int k = (lane >> 4) * 8 + i;
        int n = ct * 16 + (lane & 15);
        w2t[(ct * 2 + 1) * 512 + (e & 511)] = bfu(rg2[k * H + n] * T);
    }
    for (int e = tid; e < 2048; e += 256) {        // w1t (x 1/3)
        int i = e & 7, lane = (e >> 3) & 63, ct = e >> 9;
        int k = (lane >> 4) * 8 + i;
        int n = ct * 16 + (lane & 15);
        w1t[e] = (k < CF) ? bfu(rg1[k * H + n] * T) : (unsigned short)0;
    }
    for (int e = tid; e < 512; e += 256) {         // wct (unscaled)
        int i = e & 7, lane = e >> 3;
        int qq = lane >> 4, n = lane & 15;
        wct[e] = (n < CF && qq < 3) ? bfu(rc2[(n * CF + i) * 3 + qq])
                                    : (unsigned short)0;
    }
    __syncthreads();
    // frags that live in registers across both chunks
    short8_t wcfr = ((const short8_t*)wct)[l];
    short8_t w1fr[4];
    #pragma unroll
    for (int ct = 0; ct < 4; ++ct) w1fr[ct] = ((const short8_t*)w1t)[ct * 64 + l];
    float wA0, wB0, wC0, wA1, wB1, wC1, bb0, bb1;
    {
        int c0 = (tid & 3) * 2;
        wA0 = c1w[c0 * 3]; wB0 = c1w[c0 * 3 + 1]; wC0 = c1w[c0 * 3 + 2];
        wA1 = c1w[c0 * 3 + 3]; wB1 = c1w[c0 * 3 + 4]; wC1 = c1w[c0 * 3 + 5];
        bb0 = c1b[c0]; bb1 = c1b[c0 + 1];
    }
    __syncthreads();   // w1t/wct/raw scratch dead; chunk regions may overwrite

    // ================= persistent loop over 2 chunks ========================
    for (int it = 0; it < CPB; ++it) {
        const int chunk = blockIdx.x + it * GRID;
        const int b = chunk >> 5, ch = chunk & 31;
        const int s = ch * CHUNK;
        const bool edgeblk = (ch == 0) || (ch == NCHUNK - 1);

        // ---- phase A: stage x cols [4s-11, 4s+524] ----
        {
            const float* xb = x + (size_t)b * L0;
            for (int c = tid; c < 536; c += 256) {
                int col = 4 * s - 11 + c;
                x_l[c] = (col >= 0 && col < L0) ? xb[col] : 0.f;
            }
        }
        __syncthreads();

        // ---- phase B: conv1+relu+pool -> t1 (bf16, rows 0..265) ----
        {
            int c0 = (tid & 3) * 2;
            for (int v = tid; v < 266 * 4; v += 256) {
                int t = v >> 2;
                int g = 2 * s - 5 + t;
                unsigned o = 0;
                if (g >= 0 && g < L1) {
                    float a0 = x_l[2 * t], a1 = x_l[2 * t + 1];
                    float a2 = x_l[2 * t + 2], a3 = x_l[2 * t + 3];
                    float y00 = bb0 + wA0 * a0 + wB0 * a1 + wC0 * a2;
                    float y01 = bb0 + wA0 * a1 + wB0 * a2 + wC0 * a3;
                    float y10 = bb1 + wA1 * a0 + wB1 * a1 + wC1 * a2;
                    float y11 = bb1 + wA1 * a1 + wB1 * a2 + wC1 * a3;
                    o = pack_bf2(fmaxf(fmaxf(y00, y01), 0.f),
                                 fmaxf(fmaxf(y10, y11), 0.f));
                }
                *(unsigned*)&t1_l[t * 8 + c0] = o;
            }
        }
        __syncthreads();

        // ---- phase C: conv2 via MFMA (+bias+relu+pool) -> nd (bf16) ----
        {
            float bb2 = (m < CF) ? c2b[m] : 0.f;
            for (int rt = wave; rt < 17; rt += 4) {
                int rr = rt * 16 + m + q;
                rr = rr > 265 ? 265 : rr;
                short8_t a = *(const short8_t*)&t1_l[rr * 8];
                f32x4 c = __builtin_amdgcn_mfma_f32_16x16x32_bf16(a, wcfr, z4, 0, 0, 0);
                if (m < CF) {
                    int n0 = rt * 8 + q * 2;
                    if (n0 < 132)
                        nd_l[n0 * 8 + m] = bfu(fmaxf(fmaxf(c[0], c[1]) + bb2, 0.f));
                    if (n0 + 1 < 132)
                        nd_l[(n0 + 1) * 8 + m] = bfu(fmaxf(fmaxf(c[2], c[3]) + bb2, 0.f));
                }
            }
        }
        __syncthreads();

        // ---- phase D: GCN1 MFMA swapped; stencil B-frag built in regs ----
        // sa row rc <-> node p=s-1+rc from nd rows rc..rc+2; h1[node][feat] b64
        {
            float4 b1v[4];
            #pragma unroll
            for (int ct = 0; ct < 4; ++ct)
                b1v[ct] = *(const float4*)&g1b[ct * 16 + q * 4];
            for (int rt = wave; rt < 9; rt += 4) {
                int rc = rt * 16 + m;
                int rcc = rc > 129 ? 129 : rc;
                uint4 RL = *(const uint4*)&nd_l[rcc * 8];
                uint4 RM = *(const uint4*)&nd_l[(rcc + 1) * 8];
                uint4 RH = *(const uint4*)&nd_l[(rcc + 2) * 8];
                union { unsigned u[4]; short8_t s8; } sf;
                if (!edgeblk) {
                    sf.u[0] = pack_bf2(lof(RL.x) + lof(RM.x) + lof(RH.x),
                                       hif(RL.x) + hif(RM.x) + hif(RH.x));
                    sf.u[1] = pack_bf2(lof(RL.y) + lof(RM.y) + lof(RH.y),
                                       hif(RL.y) + hif(RM.y) + hif(RH.y));
                    sf.u[2] = pack_bf2(lof(RL.z) + lof(RM.z) + lof(RH.z),
                                       hif(RL.z) + hif(RM.z) + hif(RH.z));
                    sf.u[3] = pack_bf2(lof(RL.w) + lof(RM.w) + lof(RH.w),
                                       hif(RL.w) + hif(RM.w) + hif(RH.w));
                } else {
                    int p = s - 1 + rcc;
                    float dc = disv(p);
                    float cm_ = 3.f * dc * dc;
                    float cl_ = 3.f * dc * disv(p - 1);
                    float cr_ = 3.f * dc * disv(p + 1);
                    sf.u[0] = pack_bf2(cm_*lof(RM.x) + cl_*lof(RL.x) + cr_*lof(RH.x),
                                       cm_*hif(RM.x) + cl_*hif(RL.x) + cr_*hif(RH.x));
                    sf.u[1] = pack_bf2(cm_*lof(RM.y) + cl_*lof(RL.y) + cr_*lof(RH.y),
                                       cm_*hif(RM.y) + cl_*hif(RL.y) + cr_*hif(RH.y));
                    sf.u[2] = pack_bf2(cm_*lof(RM.z) + cl_*lof(RL.z) + cr_*lof(RH.z),
                                       cm_*hif(RM.z) + cl_*hif(RL.z) + cr_*hif(RH.z));
                    sf.u[3] = pack_bf2(cm_*lof(RM.w) + cl_*lof(RL.w) + cr_*lof(RH.w),
                                       cm_*hif(RM.w) + cl_*hif(RL.w) + cr_*hif(RH.w));
                }
                bool wok = rc < 130;
                #pragma unroll
                for (int ct = 0; ct < 4; ++ct) {
                    f32x4 c = __builtin_amdgcn_mfma_f32_16x16x32_bf16(
                        w1fr[ct], sf.s8, z4, 0, 0, 0);
                    if (wok) {
                        unsigned p01 = pack_bf2(fmaxf(c[0] + b1v[ct].x, 0.f),
                                                fmaxf(c[1] + b1v[ct].y, 0.f));
                        unsigned p23 = pack_bf2(fmaxf(c[2] + b1v[ct].z, 0.f),
                                                fmaxf(c[3] + b1v[ct].w, 0.f));
                        *(uint2*)&h1_l[rc * 72 + ct * 16 + q * 4] =
                            make_uint2(p01, p23);
                    }
                }
            }
        }
        __syncthreads();

        // ---- phase E: GCN2 MFMA (A2 = 3-row add, 1/3 in W2) + pool + fc ----
        {
            short8_t w2fr[4][2];
            float b2v[4];
            #pragma unroll
            for (int ct = 0; ct < 4; ++ct) {
                w2fr[ct][0] = ((const short8_t*)w2t)[(ct * 2 + 0) * 64 + l];
                w2fr[ct][1] = ((const short8_t*)w2t)[(ct * 2 + 1) * 64 + l];
                b2v[ct] = g2b[ct * 16 + m];
            }
            float pool_acc[4] = {0.f, 0.f, 0.f, 0.f};
            for (int rt = wave; rt < 8; rt += 4) {
                f32x4 accg[4] = {z4, z4, z4, z4};
                int r0 = rt * 16 + m;
                float cl_ = 0.f, cm_ = 0.f, cr_ = 0.f;
                if (edgeblk) {
                    int p = s + r0;
                    float dcp = disv(p);
                    cm_ = 3.f * dcp * dcp;
                    cl_ = 3.f * dcp * disv(p - 1);
                    cr_ = 3.f * dcp * disv(p + 1);
                }
                #pragma unroll
                for (int ks = 0; ks < 2; ++ks) {
                    int koff = ks * 32 + q * 8;
                    uint4 lo = *(const uint4*)&h1_l[r0 * 72 + koff];
                    uint4 mi = *(const uint4*)&h1_l[(r0 + 1) * 72 + koff];
                    uint4 hi = *(const uint4*)&h1_l[(r0 + 2) * 72 + koff];
                    union { unsigned u[4]; short8_t s8; } a2;
                    #define A2COMP(e, UL, UM, UH)                                 \
                      { float sl, sh;                                             \
                        if (!edgeblk) {                                           \
                            sl = lof(UL) + lof(UM) + lof(UH);                     \
                            sh = hif(UL) + hif(UM) + hif(UH);                     \
                        } else {                                                  \
                            sl = cm_*lof(UM) + cl_*lof(UL) + cr_*lof(UH);         \
                            sh = cm_*hif(UM) + cl_*hif(UL) + cr_*hif(UH);         \
                        }                                                         \
                        a2.u[e] = pack_bf2(sl, sh); }
                    A2COMP(0, lo.x, mi.x, hi.x)
                    A2COMP(1, lo.y, mi.y, hi.y)
                    A2COMP(2, lo.z, mi.z, hi.z)
                    A2COMP(3, lo.w, mi.w, hi.w)
                    #undef A2COMP
                    #pragma unroll
                    for (int ct = 0; ct < 4; ++ct)
                        accg[ct] = __builtin_amdgcn_mfma_f32_16x16x32_bf16(
                            a2.s8, w2fr[ct][ks], accg[ct], 0, 0, 0);
                }
                #pragma unroll
                for (int ct = 0; ct < 4; ++ct)
                    #pragma unroll
                    for (int i = 0; i < 4; ++i)
                        pool_acc[ct] += fmaxf(accg[ct][i] + b2v[ct], 0.f);
            }
            #pragma unroll
            for (int ct = 0; ct < 4; ++ct) {
                float v = pool_acc[ct];
                v += __shfl_xor(v, 16);
                v += __shfl_xor(v, 32);
                if (q == 0) red[wave * 64 + ct * 16 + m] = v;
            }
        }
        __syncthreads();

        // ---- mean-pool x fc -> atomicAdd 2 floats per chunk ----
        if (tid < H) {
            float v = red[tid] + red[64 + tid] + red[128 + tid] + red[192 + tid];
            float s0 = v * fcw[tid * 2 + 0];
            float s1 = v * fcw[tid * 2 + 1];
            #pragma unroll
            for (int o = 32; o; o >>= 1) {
                s0 += __shfl_down(s0, o);
                s1 += __shfl_down(s1, o);
            }
            if (tid == 0) {
                atomicAdd(&out[b * 2 + 0], s0 * (1.f / NPG));
                atomicAdd(&out[b * 2 + 1], s1 * (1.f / NPG));
                if (ch == 0) {
                    atomicAdd(&out[b * 2 + 0], fcb[0]);
                    atomicAdd(&out[b * 2 + 1], fcb[1]);
                }
            }
        }
    }
}

extern "C" void kernel_launch(void* const* d_in, const int* in_sizes, int n_in,
                              void* d_out, int out_size, void* d_ws, size_t ws_size,
                              hipStream_t stream) {
    (void)in_sizes; (void)n_in; (void)d_ws; (void)ws_size;
    const float* x   = (const float*)d_in[0];
    const float* c1w = (const float*)d_in[2];
    const float* c1b = (const float*)d_in[3];
    const float* c2w = (const float*)d_in[4];
    const float* c2b = (const float*)d_in[5];
    const float* g1w = (const float*)d_in[6];
    const float* g1b = (const float*)d_in[7];
    const float* g2w = (const float*)d_in[8];
    const float* g2b = (const float*)d_in[9];
    const float* fcw = (const float*)d_in[10];
    const float* fcb = (const float*)d_in[11];
    float* out = (float*)d_out;

    hipMemsetAsync(out, 0, (size_t)out_size * sizeof(float), stream);
    k_fused<<<GRID, 256, 0, stream>>>(x, c1w, c1b, c2w, c2b,
                                      g1w, g1b, g2w, g2b, fcw, fcb, out);
}

// Round 9
// 27.850 us; speedup vs baseline: 1.8277x; 1.8277x over previous
//
#include <hip/hip_runtime.h>
#include <hip/hip_bf16.h>

typedef __attribute__((ext_vector_type(8))) short short8_t;
typedef __attribute__((ext_vector_type(4))) float f32x4;

#define BATCH 64
#define L0 16384
#define L1 8192
#define NPG 4096
#define CF 8
#define H 64
#define CHUNK 128
#define NCHUNK 32
#define NCHUNKS_TOTAL 2048

// ---- LDS arena (bytes). Aliasing is time-disjoint:
//  x   [0,2144)      alive A..B      (inside h1 region)
//  t1  [2144,6400)   alive B..C      (inside h1 region)
//  w1t [11008,15104) alive prologue..C-end   (inside h1 region, h1 written in D)
//  wct [15104,16128) alive prologue..C-start (inside h1 region)
//  h1  [0,18720)     written D, read E
//  nd  [18720,20832) written C, read D
//  red [20832,21856) phase E
//  w2t [21856,30048) prologue..E (persistent)
#define A_X    0
#define A_T1   2144
#define P_W1T  11008
#define P_WCT  15104
#define A_H1   0
#define A_ND   18720
#define A_RED  20832
#define A_W2T  21856
#define ARENA_BYTES 30048

__device__ __forceinline__ float disv(int p) {
    if (p < 0 || p >= NPG) return 0.f;
    if (p == 0 || p == NPG - 1) return 0.70710678118654752f;  // 1/sqrt(2)
    return 0.57735026918962576f;                              // 1/sqrt(3)
}
__device__ __forceinline__ unsigned pack_bf2(float a, float b) {
    union { __hip_bfloat162 h2; unsigned u; } cv;
    cv.h2 = __float22bfloat162_rn(make_float2(a, b));
    return cv.u;
}
__device__ __forceinline__ unsigned short bfu(float f) {
    union { __hip_bfloat16 h; unsigned short u; } cv;
    cv.h = __float2bfloat16(f);
    return cv.u;
}
__device__ __forceinline__ float lof(unsigned u) { return __uint_as_float(u << 16); }
__device__ __forceinline__ float hif(unsigned u) { return __uint_as_float(u & 0xffff0000u); }

// Fused: conv1+pool -> conv2(MFMA)+pool -> GCN1(MFMA swapped, stencil in regs)
// -> GCN2(MFMA) -> mean-pool partials. One block per 128-node chunk.
__global__ __launch_bounds__(256, 5) void k_fused(const float* __restrict__ x,
        const float* __restrict__ c1w, const float* __restrict__ c1b,
        const float* __restrict__ c2w, const float* __restrict__ c2b,
        const float* __restrict__ g1w, const float* __restrict__ g1b,
        const float* __restrict__ g2w, const float* __restrict__ g2b,
        float* __restrict__ partials) {
    __shared__ __align__(16) char arena[ARENA_BYTES];
    float*          x_l  = (float*)(arena + A_X);
    unsigned short* t1_l = (unsigned short*)(arena + A_T1);
    unsigned short* nd_l = (unsigned short*)(arena + A_ND);
    unsigned short* h1_l = (unsigned short*)(arena + A_H1);
    unsigned short* w2t  = (unsigned short*)(arena + A_W2T);
    unsigned short* w1t  = (unsigned short*)(arena + P_W1T);
    unsigned short* wct  = (unsigned short*)(arena + P_WCT);
    float*          red  = (float*)(arena + A_RED);

    const int tid = threadIdx.x;
    const int wave = tid >> 6;
    const int l = tid & 63;
    const int m = l & 15, q = l >> 4;
    const float T = 1.f / 3.f;
    const f32x4 z4 = {0.f, 0.f, 0.f, 0.f};

    const int chunk = blockIdx.x;
    const int b = chunk >> 5, ch = chunk & 31;
    const int s = ch * CHUNK;
    const bool edgeblk = (ch == 0) || (ch == NCHUNK - 1);

    // ---- prologue: frag tables from SOURCE-COALESCED global reads ----
    // zero-init w1t (4096 B) + wct (1024 B) with wide stores
    {
        uint4 z = {0u, 0u, 0u, 0u};
        *(uint4*)&w1t[tid * 8] = z;                    // 256*16B = 4096
        if (tid < 64) *(uint4*)&wct[tid * 8] = z;      // 1024
    }
    // w2t[ct][ks][lane][i] = g2w[k][n]/3, k=ks*32+qq*8+i, n=ct*16+(lane&15)
    #pragma unroll
    for (int j = 0; j < 16; ++j) {
        int e = tid + 256 * j;                         // g2w flat index
        int k = e >> 6, n = e & 63;
        int ks = k >> 5, rem = k & 31, qq = rem >> 3, i = rem & 7;
        int lane = qq * 16 + (n & 15), ct = n >> 4;
        w2t[((ct * 2 + ks) * 64 + lane) * 8 + i] = bfu(g2w[e] * T);
    }
    __syncthreads();   // cover the zero-inits before scatter-fill of w1t/wct
    #pragma unroll
    for (int j = 0; j < 2; ++j) {
        int e = tid + 256 * j;                         // g1w flat (512)
        int k = e >> 6, n = e & 63;                    // k<8 -> qq=0, i=k
        w1t[((n >> 4) * 64 + (n & 15)) * 8 + k] = bfu(g1w[e] * T);
    }
    if (tid < 192) {                                   // c2w flat (192)
        int co = tid / 24, rem2 = tid % 24, ci = rem2 / 3, tap = rem2 % 3;
        wct[(tap * 16 + co) * 8 + ci] = bfu(c2w[tid]);
    }

    // ---- phase A: stage x cols [4s-11, 4s+524] ----
    {
        const float* xb = x + (size_t)b * L0;
        for (int c = tid; c < 536; c += 256) {
            int col = 4 * s - 11 + c;
            x_l[c] = (col >= 0 && col < L0) ? xb[col] : 0.f;
        }
    }
    __syncthreads();

    // ---- phase B: conv1+relu+pool -> t1 (bf16, rows 0..265) ----
    {
        int c0 = (tid & 3) * 2;
        float wA0 = c1w[c0 * 3], wB0 = c1w[c0 * 3 + 1], wC0 = c1w[c0 * 3 + 2];
        float wA1 = c1w[c0 * 3 + 3], wB1 = c1w[c0 * 3 + 4], wC1 = c1w[c0 * 3 + 5];
        float bb0 = c1b[c0], bb1 = c1b[c0 + 1];
        for (int v = tid; v < 266 * 4; v += 256) {
            int t = v >> 2;
            int g = 2 * s - 5 + t;
            unsigned o = 0;
            if (g >= 0 && g < L1) {
                float a0 = x_l[2 * t], a1 = x_l[2 * t + 1];
                float a2 = x_l[2 * t + 2], a3 = x_l[2 * t + 3];
                float y00 = bb0 + wA0 * a0 + wB0 * a1 + wC0 * a2;
                float y01 = bb0 + wA0 * a1 + wB0 * a2 + wC0 * a3;
                float y10 = bb1 + wA1 * a0 + wB1 * a1 + wC1 * a2;
                float y11 = bb1 + wA1 * a1 + wB1 * a2 + wC1 * a3;
                o = pack_bf2(fmaxf(fmaxf(y00, y01), 0.f),
                             fmaxf(fmaxf(y10, y11), 0.f));
            }
            *(unsigned*)&t1_l[t * 8 + c0] = o;
        }
    }
    __syncthreads();

    // ---- phase C: conv2 via MFMA (+bias+relu+pool) -> nd (bf16) ----
    short8_t w1fr[4];
    {
        short8_t wcfr = ((const short8_t*)wct)[l];
        float bb2 = (m < CF) ? c2b[m] : 0.f;
        for (int rt = wave; rt < 17; rt += 4) {
            int rr = rt * 16 + m + q;
            rr = rr > 265 ? 265 : rr;
            short8_t a = *(const short8_t*)&t1_l[rr * 8];
            f32x4 c = __builtin_amdgcn_mfma_f32_16x16x32_bf16(a, wcfr, z4, 0, 0, 0);
            if (m < CF) {
                int n0 = rt * 8 + q * 2;
                if (n0 < 132)
                    nd_l[n0 * 8 + m] = bfu(fmaxf(fmaxf(c[0], c[1]) + bb2, 0.f));
                if (n0 + 1 < 132)
                    nd_l[(n0 + 1) * 8 + m] = bfu(fmaxf(fmaxf(c[2], c[3]) + bb2, 0.f));
            }
        }
        // load w1 frags BEFORE the barrier (w1t region is overwritten by h1 in D)
        #pragma unroll
        for (int ct = 0; ct < 4; ++ct)
            w1fr[ct] = ((const short8_t*)w1t)[ct * 64 + l];
    }
    __syncthreads();

    // ---- phase D: GCN1 MFMA swapped (D = W1^T x stencil^T); frag in regs ----
    {
        float4 b1v[4];
        #pragma unroll
        for (int ct = 0; ct < 4; ++ct)
            b1v[ct] = *(const float4*)&g1b[ct * 16 + q * 4];
        for (int rt = wave; rt < 9; rt += 4) {
            int rc = rt * 16 + m;
            int rcc = rc > 129 ? 129 : rc;
            uint4 RL = *(const uint4*)&nd_l[rcc * 8];
            uint4 RM = *(const uint4*)&nd_l[(rcc + 1) * 8];
            uint4 RH = *(const uint4*)&nd_l[(rcc + 2) * 8];
            union { unsigned u[4]; short8_t s8; } sf;
            if (!edgeblk) {
                sf.u[0] = pack_bf2(lof(RL.x) + lof(RM.x) + lof(RH.x),
                                   hif(RL.x) + hif(RM.x) + hif(RH.x));
                sf.u[1] = pack_bf2(lof(RL.y) + lof(RM.y) + lof(RH.y),
                                   hif(RL.y) + hif(RM.y) + hif(RH.y));
                sf.u[2] = pack_bf2(lof(RL.z) + lof(RM.z) + lof(RH.z),
                                   hif(RL.z) + hif(RM.z) + hif(RH.z));
                sf.u[3] = pack_bf2(lof(RL.w) + lof(RM.w) + lof(RH.w),
                                   hif(RL.w) + hif(RM.w) + hif(RH.w));
            } else {
                int p = s - 1 + rcc;
                float dc = disv(p);
                float cm_ = 3.f * dc * dc;
                float cl_ = 3.f * dc * disv(p - 1);
                float cr_ = 3.f * dc * disv(p + 1);
                sf.u[0] = pack_bf2(cm_*lof(RM.x) + cl_*lof(RL.x) + cr_*lof(RH.x),
                                   cm_*hif(RM.x) + cl_*hif(RL.x) + cr_*hif(RH.x));
                sf.u[1] = pack_bf2(cm_*lof(RM.y) + cl_*lof(RL.y) + cr_*lof(RH.y),
                                   cm_*hif(RM.y) + cl_*hif(RL.y) + cr_*hif(RH.y));
                sf.u[2] = pack_bf2(cm_*lof(RM.z) + cl_*lof(RL.z) + cr_*lof(RH.z),
                                   cm_*hif(RM.z) + cl_*hif(RL.z) + cr_*hif(RH.z));
                sf.u[3] = pack_bf2(cm_*lof(RM.w) + cl_*lof(RL.w) + cr_*lof(RH.w),
                                   cm_*hif(RM.w) + cl_*hif(RL.w) + cr_*hif(RH.w));
            }
            bool wok = rc < 130;
            #pragma unroll
            for (int ct = 0; ct < 4; ++ct) {
                f32x4 c = __builtin_amdgcn_mfma_f32_16x16x32_bf16(
                    w1fr[ct], sf.s8, z4, 0, 0, 0);
                if (wok) {
                    unsigned p01 = pack_bf2(fmaxf(c[0] + b1v[ct].x, 0.f),
                                            fmaxf(c[1] + b1v[ct].y, 0.f));
                    unsigned p23 = pack_bf2(fmaxf(c[2] + b1v[ct].z, 0.f),
                                            fmaxf(c[3] + b1v[ct].w, 0.f));
                    *(uint2*)&h1_l[rc * 72 + ct * 16 + q * 4] = make_uint2(p01, p23);
                }
            }
        }
    }
    __syncthreads();

    // ---- phase E: GCN2 MFMA (A2 = 3-row add, 1/3 in W2) + relu + pool ----
    {
        short8_t w2fr[4][2];
        float b2v[4];
        #pragma unroll
        for (int ct = 0; ct < 4; ++ct) {
            w2fr[ct][0] = ((const short8_t*)w2t)[(ct * 2 + 0) * 64 + l];
            w2fr[ct][1] = ((const short8_t*)w2t)[(ct * 2 + 1) * 64 + l];
            b2v[ct] = g2b[ct * 16 + m];
        }
        float pool_acc[4] = {0.f, 0.f, 0.f, 0.f};
        for (int rt = wave; rt < 8; rt += 4) {
            f32x4 accg[4] = {z4, z4, z4, z4};
            int r0 = rt * 16 + m;
            float cl_ = 0.f, cm_ = 0.f, cr_ = 0.f;
            if (edgeblk) {
                int p = s + r0;
                float dcp = disv(p);
                cm_ = 3.f * dcp * dcp;
                cl_ = 3.f * dcp * disv(p - 1);
                cr_ = 3.f * dcp * disv(p + 1);
            }
            #pragma unroll
            for (int ks = 0; ks < 2; ++ks) {
                int koff = ks * 32 + q * 8;
                uint4 lo = *(const uint4*)&h1_l[r0 * 72 + koff];
                uint4 mi = *(const uint4*)&h1_l[(r0 + 1) * 72 + koff];
                uint4 hi = *(const uint4*)&h1_l[(r0 + 2) * 72 + koff];
                union { unsigned u[4]; short8_t s8; } a2;
                #define A2COMP(e, UL, UM, UH)                                 \
                  { float sl, sh;                                             \
                    if (!edgeblk) {                                           \
                        sl = lof(UL) + lof(UM) + lof(UH);                     \
                        sh = hif(UL) + hif(UM) + hif(UH);                     \
                    } else {                                                  \
                        sl = cm_*lof(UM) + cl_*lof(UL) + cr_*lof(UH);         \
                        sh = cm_*hif(UM) + cl_*hif(UL) + cr_*hif(UH);         \
                    }                                                         \
                    a2.u[e] = pack_bf2(sl, sh); }
                A2COMP(0, lo.x, mi.x, hi.x)
                A2COMP(1, lo.y, mi.y, hi.y)
                A2COMP(2, lo.z, mi.z, hi.z)
                A2COMP(3, lo.w, mi.w, hi.w)
                #undef A2COMP
                #pragma unroll
                for (int ct = 0; ct < 4; ++ct)
                    accg[ct] = __builtin_amdgcn_mfma_f32_16x16x32_bf16(
                        a2.s8, w2fr[ct][ks], accg[ct], 0, 0, 0);
            }
            #pragma unroll
            for (int ct = 0; ct < 4; ++ct)
                #pragma unroll
                for (int i = 0; i < 4; ++i)
                    pool_acc[ct] += fmaxf(accg[ct][i] + b2v[ct], 0.f);
        }
        #pragma unroll
        for (int ct = 0; ct < 4; ++ct) {
            float v = pool_acc[ct];
            v += __shfl_xor(v, 16);
            v += __shfl_xor(v, 32);
            if (q == 0) red[wave * 64 + ct * 16 + m] = v;
        }
    }
    __syncthreads();
    if (tid < H) {
        partials[(size_t)chunk * H + tid] = red[tid] + red[64 + tid]
                                          + red[128 + tid] + red[192 + tid];
    }
}

// per-graph reduce over chunks + mean + fc
__global__ __launch_bounds__(256) void k_final(const float* __restrict__ partials,
        const float* __restrict__ fcw, const float* __restrict__ fcb,
        float* __restrict__ out) {
    __shared__ float red[4][H];
    __shared__ float pool_l[H];
    int bgr = blockIdx.x;
    int tid = threadIdx.x;
    int g = tid >> 6, j = tid & 63;
    float acc = 0.f;
    for (int c = g; c < NCHUNK; c += 4)
        acc += partials[((size_t)bgr * NCHUNK + c) * H + j];
    red[g][j] = acc;
    __syncthreads();
    if (tid < H)
        pool_l[j] = (red[0][j] + red[1][j] + red[2][j] + red[3][j]) * (1.f / NPG);
    __syncthreads();
    if (tid < 2) {
        float o = fcb[tid];
        for (int k = 0; k < H; ++k) o += pool_l[k] * fcw[k * 2 + tid];
        out[bgr * 2 + tid] = o;
    }
}

extern "C" void kernel_launch(void* const* d_in, const int* in_sizes, int n_in,
                              void* d_out, int out_size, void* d_ws, size_t ws_size,
                              hipStream_t stream) {
    (void)in_sizes; (void)n_in; (void)out_size; (void)ws_size;
    const float* x   = (const float*)d_in[0];
    const float* c1w = (const float*)d_in[2];
    const float* c1b = (const float*)d_in[3];
    const float* c2w = (const float*)d_in[4];
    const float* c2b = (const float*)d_in[5];
    const float* g1w = (const float*)d_in[6];
    const float* g1b = (const float*)d_in[7];
    const float* g2w = (const float*)d_in[8];
    const float* g2b = (const float*)d_in[9];
    const float* fcw = (const float*)d_in[10];
    const float* fcb = (const float*)d_in[11];
    float* out = (float*)d_out;

    float* partials = (float*)d_ws;     // [2048][64] f32 = 512 KB

    k_fused<<<NCHUNKS_TOTAL, 256, 0, stream>>>(x, c1w, c1b, c2w, c2b,
                                               g1w, g1b, g2w, g2b, partials);
    k_final<<<BATCH, 256, 0, stream>>>(partials, fcw, fcb, out);
}

// Round 10
// 25.365 us; speedup vs baseline: 2.0067x; 1.0979x over previous
//
#include <hip/hip_runtime.h>
#include <hip/hip_fp16.h>

typedef _Float16 half8 __attribute__((ext_vector_type(8)));
typedef __attribute__((ext_vector_type(4))) float f32x4;

#define BATCH 64
#define L0 16384
#define L1 8192
#define NPG 4096
#define CF 8
#define H 64
#define CHUNK 128
#define NCHUNK 32
#define NCHUNKS_TOTAL 2048

// ---- LDS arena (bytes), same time-disjoint aliasing as R9 ----
#define A_X    0
#define A_T1   2144
#define P_W1T  11008
#define P_WCT  15104
#define A_H1   0
#define A_ND   18720
#define A_RED  20832
#define A_W2T  21856
#define ARENA_BYTES 30048

__device__ __forceinline__ float disv(int p) {
    if (p < 0 || p >= NPG) return 0.f;
    if (p == 0 || p == NPG - 1) return 0.70710678118654752f;  // 1/sqrt(2)
    return 0.57735026918962576f;                              // 1/sqrt(3)
}
// f32x2 -> packed fp16x2 (RNE)
__device__ __forceinline__ unsigned packh2(float a, float b) {
    union { __half2 h; unsigned u; } cv;
    cv.h = __float22half2_rn(make_float2(a, b));
    return cv.u;
}
__device__ __forceinline__ unsigned short h1u(float f) {
    union { __half h; unsigned short u; } cv;
    cv.h = __float2half_rn(f);
    return cv.u;
}
// packed 3-way fp16 add: 2 x v_pk_add_f16
__device__ __forceinline__ unsigned pkadd3(unsigned a, unsigned b, unsigned c) {
    union { unsigned u; __half2 h; } A, B, C, R;
    A.u = a; B.u = b; C.u = c;
    R.h = __hadd2(__hadd2(A.h, B.h), C.h);
    return R.u;
}
__device__ __forceinline__ float2 uph2(unsigned u) {
    union { unsigned uu; __half2 h; } cv; cv.uu = u;
    return __half22float2(cv.h);
}

// Fused: conv1+pool -> conv2(MFMA)+pool -> GCN1(MFMA swapped) -> GCN2(MFMA)
// -> mean-pool partials. All intermediates fp16 (packed-add stencils).
__global__ __launch_bounds__(256, 5) void k_fused(const float* __restrict__ x,
        const float* __restrict__ c1w, const float* __restrict__ c1b,
        const float* __restrict__ c2w, const float* __restrict__ c2b,
        const float* __restrict__ g1w, const float* __restrict__ g1b,
        const float* __restrict__ g2w, const float* __restrict__ g2b,
        float* __restrict__ partials) {
    __shared__ __align__(16) char arena[ARENA_BYTES];
    float*          x_l  = (float*)(arena + A_X);
    unsigned short* t1_l = (unsigned short*)(arena + A_T1);
    unsigned short* nd_l = (unsigned short*)(arena + A_ND);
    unsigned short* h1_l = (unsigned short*)(arena + A_H1);
    unsigned short* w2t  = (unsigned short*)(arena + A_W2T);
    unsigned short* w1t  = (unsigned short*)(arena + P_W1T);
    unsigned short* wct  = (unsigned short*)(arena + P_WCT);
    float*          red  = (float*)(arena + A_RED);
    unsigned* w2t32 = (unsigned*)w2t;
    unsigned* w1t32 = (unsigned*)w1t;

    const int tid = threadIdx.x;
    const int wave = tid >> 6;
    const int l = tid & 63;
    const int m = l & 15, q = l >> 4;
    const float T = 1.f / 3.f;
    const f32x4 z4 = {0.f, 0.f, 0.f, 0.f};

    const int chunk = blockIdx.x;
    const int b = chunk >> 5, ch = chunk & 31;
    const int s = ch * CHUNK;
    const bool edgeblk = (ch == 0) || (ch == NCHUNK - 1);

    // ---- prologue: frag tables from source-coalesced reads, pair-packed ----
    {
        uint4 z = {0u, 0u, 0u, 0u};
        *(uint4*)&w1t[tid * 8] = z;                    // 4096 B
        if (tid < 64) *(uint4*)&wct[tid * 8] = z;      // 1024 B
    }
    // w2t: pairs (k,k+1) -> one u32; p = (ks,qq,i2,n)
    #pragma unroll
    for (int j = 0; j < 8; ++j) {
        int p = tid + 256 * j;
        int n = p & 63, rest = p >> 6;
        int i2 = rest & 3, qq = (rest >> 2) & 3, ks = rest >> 4;
        int e0 = (ks * 32 + qq * 8 + 2 * i2) * 64 + n;
        int lane = qq * 16 + (n & 15), ct = n >> 4;
        w2t32[((ct * 2 + ks) * 64 + lane) * 4 + i2] =
            packh2(g2w[e0] * T, g2w[e0 + 64] * T);
    }
    __syncthreads();   // cover zero-inits before partial fills
    {   // w1t: lanes 0..15 only (qq=0), pairs
        int n = tid & 63, i2 = tid >> 6;
        int e0 = (2 * i2) * 64 + n;
        w1t32[((n >> 4) * 64 + (n & 15)) * 4 + i2] =
            packh2(g1w[e0] * T, g1w[e0 + 64] * T);
    }
    if (tid < 192) {                                   // c2w flat (192)
        int co = tid / 24, rem2 = tid % 24, ci = rem2 / 3, tap = rem2 % 3;
        wct[(tap * 16 + co) * 8 + ci] = h1u(c2w[tid]);
    }

    // ---- phase A: stage x cols [4s-11, 4s+524] ----
    {
        const float* xb = x + (size_t)b * L0;
        for (int c = tid; c < 536; c += 256) {
            int col = 4 * s - 11 + c;
            x_l[c] = (col >= 0 && col < L0) ? xb[col] : 0.f;
        }
    }
    __syncthreads();

    // ---- phase B: conv1+relu+pool -> t1 (fp16, rows 0..265) ----
    {
        int c0 = (tid & 3) * 2;
        float wA0 = c1w[c0 * 3], wB0 = c1w[c0 * 3 + 1], wC0 = c1w[c0 * 3 + 2];
        float wA1 = c1w[c0 * 3 + 3], wB1 = c1w[c0 * 3 + 4], wC1 = c1w[c0 * 3 + 5];
        float bb0 = c1b[c0], bb1 = c1b[c0 + 1];
        for (int v = tid; v < 266 * 4; v += 256) {
            int t = v >> 2;
            int g = 2 * s - 5 + t;
            unsigned o = 0;
            if (g >= 0 && g < L1) {
                float a0 = x_l[2 * t], a1 = x_l[2 * t + 1];
                float a2 = x_l[2 * t + 2], a3 = x_l[2 * t + 3];
                float y00 = bb0 + wA0 * a0 + wB0 * a1 + wC0 * a2;
                float y01 = bb0 + wA0 * a1 + wB0 * a2 + wC0 * a3;
                float y10 = bb1 + wA1 * a0 + wB1 * a1 + wC1 * a2;
                float y11 = bb1 + wA1 * a1 + wB1 * a2 + wC1 * a3;
                o = packh2(fmaxf(fmaxf(y00, y01), 0.f),
                           fmaxf(fmaxf(y10, y11), 0.f));
            }
            *(unsigned*)&t1_l[t * 8 + c0] = o;
        }
    }
    __syncthreads();

    // ---- phase C: conv2 via MFMA (+bias+relu+pool) -> nd (fp16) ----
    half8 w1fr[4];
    {
        half8 wcfr = ((const half8*)wct)[l];
        float bb2 = (m < CF) ? c2b[m] : 0.f;
        for (int rt = wave; rt < 17; rt += 4) {
            int rr = rt * 16 + m + q;
            rr = rr > 265 ? 265 : rr;
            half8 a = *(const half8*)&t1_l[rr * 8];
            f32x4 c = __builtin_amdgcn_mfma_f32_16x16x32_f16(a, wcfr, z4, 0, 0, 0);
            if (m < CF) {
                int n0 = rt * 8 + q * 2;
                if (n0 < 132)
                    nd_l[n0 * 8 + m] = h1u(fmaxf(fmaxf(c[0], c[1]) + bb2, 0.f));
                if (n0 + 1 < 132)
                    nd_l[(n0 + 1) * 8 + m] = h1u(fmaxf(fmaxf(c[2], c[3]) + bb2, 0.f));
            }
        }
        // load w1 frags BEFORE the barrier (w1t region overwritten by h1 in D)
        #pragma unroll
        for (int ct = 0; ct < 4; ++ct)
            w1fr[ct] = ((const half8*)w1t)[ct * 64 + l];
    }
    __syncthreads();

    // ---- phase D: GCN1 MFMA swapped (D = W1^T x stencil^T); pk-add stencil ----
    {
        float4 b1v[4];
        #pragma unroll
        for (int ct = 0; ct < 4; ++ct)
            b1v[ct] = *(const float4*)&g1b[ct * 16 + q * 4];
        for (int rt = wave; rt < 9; rt += 4) {
            int rc = rt * 16 + m;
            int rcc = rc > 129 ? 129 : rc;
            uint4 RL = *(const uint4*)&nd_l[rcc * 8];
            uint4 RM = *(const uint4*)&nd_l[(rcc + 1) * 8];
            uint4 RH = *(const uint4*)&nd_l[(rcc + 2) * 8];
            union { unsigned u[4]; half8 h8; } sf;
            if (!edgeblk) {
                sf.u[0] = pkadd3(RL.x, RM.x, RH.x);
                sf.u[1] = pkadd3(RL.y, RM.y, RH.y);
                sf.u[2] = pkadd3(RL.z, RM.z, RH.z);
                sf.u[3] = pkadd3(RL.w, RM.w, RH.w);
            } else {
                int p = s - 1 + rcc;
                float dc = disv(p);
                float cm_ = 3.f * dc * dc;
                float cl_ = 3.f * dc * disv(p - 1);
                float cr_ = 3.f * dc * disv(p + 1);
                #define SFE(e, UL, UM, UH)                                        \
                  { float2 Lf = uph2(UL), Mf = uph2(UM), Hf = uph2(UH);           \
                    sf.u[e] = packh2(cm_*Mf.x + cl_*Lf.x + cr_*Hf.x,              \
                                     cm_*Mf.y + cl_*Lf.y + cr_*Hf.y); }
                SFE(0, RL.x, RM.x, RH.x)
                SFE(1, RL.y, RM.y, RH.y)
                SFE(2, RL.z, RM.z, RH.z)
                SFE(3, RL.w, RM.w, RH.w)
                #undef SFE
            }
            bool wok = rc < 130;
            #pragma unroll
            for (int ct = 0; ct < 4; ++ct) {
                f32x4 c = __builtin_amdgcn_mfma_f32_16x16x32_f16(
                    w1fr[ct], sf.h8, z4, 0, 0, 0);
                if (wok) {
                    unsigned p01 = packh2(fmaxf(c[0] + b1v[ct].x, 0.f),
                                          fmaxf(c[1] + b1v[ct].y, 0.f));
                    unsigned p23 = packh2(fmaxf(c[2] + b1v[ct].z, 0.f),
                                          fmaxf(c[3] + b1v[ct].w, 0.f));
                    *(uint2*)&h1_l[rc * 72 + ct * 16 + q * 4] = make_uint2(p01, p23);
                }
            }
        }
    }
    __syncthreads();

    // ---- phase E: GCN2 MFMA (A2 = pk-add of 3 h1 rows, 1/3 in W2) + pool ----
    {
        half8 w2fr[4][2];
        float b2v[4];
        #pragma unroll
        for (int ct = 0; ct < 4; ++ct) {
            w2fr[ct][0] = ((const half8*)w2t)[(ct * 2 + 0) * 64 + l];
            w2fr[ct][1] = ((const half8*)w2t)[(ct * 2 + 1) * 64 + l];
            b2v[ct] = g2b[ct * 16 + m];
        }
        float pool_acc[4] = {0.f, 0.f, 0.f, 0.f};
        for (int rt = wave; rt < 8; rt += 4) {
            f32x4 accg[4] = {z4, z4, z4, z4};
            int r0 = rt * 16 + m;
            float cl_ = 0.f, cm_ = 0.f, cr_ = 0.f;
            if (edgeblk) {
                int p = s + r0;
                float dcp = disv(p);
                cm_ = 3.f * dcp * dcp;
                cl_ = 3.f * dcp * disv(p - 1);
                cr_ = 3.f * dcp * disv(p + 1);
            }
            #pragma unroll
            for (int ks = 0; ks < 2; ++ks) {
                int koff = ks * 32 + q * 8;
                uint4 lo = *(const uint4*)&h1_l[r0 * 72 + koff];
                uint4 mi = *(const uint4*)&h1_l[(r0 + 1) * 72 + koff];
                uint4 hi = *(const uint4*)&h1_l[(r0 + 2) * 72 + koff];
                union { unsigned u[4]; half8 h8; } a2;
                if (!edgeblk) {
                    a2.u[0] = pkadd3(lo.x, mi.x, hi.x);
                    a2.u[1] = pkadd3(lo.y, mi.y, hi.y);
                    a2.u[2] = pkadd3(lo.z, mi.z, hi.z);
                    a2.u[3] = pkadd3(lo.w, mi.w, hi.w);
                } else {
                    #define A2E(e, UL, UM, UH)                                    \
                      { float2 Lf = uph2(UL), Mf = uph2(UM), Hf = uph2(UH);       \
                        a2.u[e] = packh2(cm_*Mf.x + cl_*Lf.x + cr_*Hf.x,          \
                                         cm_*Mf.y + cl_*Lf.y + cr_*Hf.y); }
                    A2E(0, lo.x, mi.x, hi.x)
                    A2E(1, lo.y, mi.y, hi.y)
                    A2E(2, lo.z, mi.z, hi.z)
                    A2E(3, lo.w, mi.w, hi.w)
                    #undef A2E
                }
                #pragma unroll
                for (int ct = 0; ct < 4; ++ct)
                    accg[ct] = __builtin_amdgcn_mfma_f32_16x16x32_f16(
                        a2.h8, w2fr[ct][ks], accg[ct], 0, 0, 0);
            }
            #pragma unroll
            for (int ct = 0; ct < 4; ++ct)
                #pragma unroll
                for (int i = 0; i < 4; ++i)
                    pool_acc[ct] += fmaxf(accg[ct][i] + b2v[ct], 0.f);
        }
        #pragma unroll
        for (int ct = 0; ct < 4; ++ct) {
            float v = pool_acc[ct];
            v += __shfl_xor(v, 16);
            v += __shfl_xor(v, 32);
            if (q == 0) red[wave * 64 + ct * 16 + m] = v;
        }
    }
    __syncthreads();
    if (tid < H) {
        partials[(size_t)chunk * H + tid] = red[tid] + red[64 + tid]
                                          + red[128 + tid] + red[192 + tid];
    }
}

// per-graph reduce over chunks + mean + fc
__global__ __launch_bounds__(256) void k_final(const float* __restrict__ partials,
        const float* __restrict__ fcw, const float* __restrict__ fcb,
        float* __restrict__ out) {
    __shared__ float red[4][H];
    __shared__ float pool_l[H];
    int bgr = blockIdx.x;
    int tid = threadIdx.x;
    int g = tid >> 6, j = tid & 63;
    float acc = 0.f;
    for (int c = g; c < NCHUNK; c += 4)
        acc += partials[((size_t)bgr * NCHUNK + c) * H + j];
    red[g][j] = acc;
    __syncthreads();
    if (tid < H)
        pool_l[j] = (red[0][j] + red[1][j] + red[2][j] + red[3][j]) * (1.f / NPG);
    __syncthreads();
    if (tid < 2) {
        float o = fcb[tid];
        for (int k = 0; k < H; ++k) o += pool_l[k] * fcw[k * 2 + tid];
        out[bgr * 2 + tid] = o;
    }
}

extern "C" void kernel_launch(void* const* d_in, const int* in_sizes, int n_in,
                              void* d_out, int out_size, void* d_ws, size_t ws_size,
                              hipStream_t stream) {
    (void)in_sizes; (void)n_in; (void)out_size; (void)ws_size;
    const float* x   = (const float*)d_in[0];
    const float* c1w = (const float*)d_in[2];
    const float* c1b = (const float*)d_in[3];
    const float* c2w = (const float*)d_in[4];
    const float* c2b = (const float*)d_in[5];
    const float* g1w = (const float*)d_in[6];
    const float* g1b = (const float*)d_in[7];
    const float* g2w = (const float*)d_in[8];
    const float* g2b = (const float*)d_in[9];
    const float* fcw = (const float*)d_in[10];
    const float* fcb = (const float*)d_in[11];
    float* out = (float*)d_out;

    float* partials = (float*)d_ws;     // [2048][64] f32 = 512 KB

    k_fused<<<NCHUNKS_TOTAL, 256, 0, stream>>>(x, c1w, c1b, c2w, c2b,
                                               g1w, g1b, g2w, g2b, partials);
    k_final<<<BATCH, 256, 0, stream>>>(partials, fcw, fcb, out);
}